// Round 3
// baseline (2653.721 us; speedup 1.0000x reference)
//
#include <hip/hip_runtime.h>
#include <stdint.h>
#include <stddef.h>

#define T_SEQ 512
#define HDIM 512
#define CTXN 10
#define OUT_T (T_SEQ - 2 * CTXN)   // 492
#define GM 16
#define GC 16
#define NSLOT 8192                 // GM*HDIM u64 words per ring slot

typedef __bf16 bf16x8 __attribute__((ext_vector_type(8)));
typedef float f32x4 __attribute__((ext_vector_type(4)));
typedef unsigned short u16x4 __attribute__((ext_vector_type(4)));
typedef unsigned short u16x8 __attribute__((ext_vector_type(8)));
typedef unsigned long long u64;

__device__ __forceinline__ unsigned short f2bf(float f) {
  union { float f; unsigned u; } v; v.f = f;
  unsigned r = v.u + 0x7FFFu + ((v.u >> 16) & 1u);  // RNE
  return (unsigned short)(r >> 16);
}
__device__ __forceinline__ float bf2f(unsigned short b) {
  union { unsigned u; float f; } v; v.u = ((unsigned)b) << 16;
  return v.f;
}

// LDS-only barrier: orders ds ops across the workgroup WITHOUT draining vmcnt.
// (__syncthreads emits s_waitcnt vmcnt(0) — that forced every step's scattered
// out-stores and h-stores into the critical path.)  m201-verified pattern.
__device__ __forceinline__ void lds_barrier() {
  asm volatile("s_waitcnt lgkmcnt(0)" ::: "memory");
  __builtin_amdgcn_s_barrier();
  __builtin_amdgcn_sched_barrier(0);
}

// ------------- split fp32 weights into (hi, lo) bf16 pairs -------------
__global__ void split_w(const float* __restrict__ wih_f, const float* __restrict__ wih_b,
                        const float* __restrict__ whh_f, const float* __restrict__ whh_b,
                        unsigned short* __restrict__ wih_hi, unsigned short* __restrict__ wih_lo,
                        unsigned short* __restrict__ whh_hi, unsigned short* __restrict__ whh_lo) {
  const int which = blockIdx.y;
  const float* src = which == 0 ? wih_f : which == 1 ? wih_b : which == 2 ? whh_f : whh_b;
  const size_t off = (which & 1) ? (size_t)1536 * HDIM : 0;
  unsigned short* dhi = (which < 2 ? wih_hi : whh_hi) + off;
  unsigned short* dlo = (which < 2 ? wih_lo : whh_lo) + off;
  size_t i = ((size_t)blockIdx.x * 256 + threadIdx.x) * 4;
  float4 v = *(const float4*)(src + i);
  u16x4 h, l;
  h.x = f2bf(v.x); l.x = f2bf(v.x - bf2f(h.x));
  h.y = f2bf(v.y); l.y = f2bf(v.y - bf2f(h.y));
  h.z = f2bf(v.z); l.z = f2bf(v.z - bf2f(h.z));
  h.w = f2bf(v.w); l.w = f2bf(v.w - bf2f(h.w));
  *(u16x4*)(dhi + i) = h;
  *(u16x4*)(dlo + i) = l;
}

// ------------- fused split-precision bidirectional GRU recurrence -------------
// 8 groups = (4 batch chunks of 16) x (2 dirs); 32 blocks/group.
// h exchange: tagged u64 {tag=step | (hi16|lo16)} in a depth-2 ring, wire
// layout = MFMA fragment order (coalesced both sides).  Changes vs r2:
//   * poll re-issues ALL 32 words per round (kills serialized stale retries)
//   * LDS-only barriers (no per-step vmcnt(0) drain; stores fire-and-forget)
//   * gh waves = 4..7, gates = waves 0..3; gh pre-issues next step's loads
//     between the barriers (speculative, tag-checked)
//   * gates: __expf / __fdividef, h and biases in registers
// Depth-2 safety (unchanged): a block stores tag s+1 only after observing all
// tags==s, which implies every block retired its slot((s+1)&1) reads.
// In-flight stores across the raw barrier are safe: readers poll tags, and
// same-thread same-address stores (slot wraparound) retire in order.
__global__ __launch_bounds__(512)
void gru_rec(const float* __restrict__ x,
             const unsigned short* __restrict__ wih_hi, const unsigned short* __restrict__ wih_lo,
             const unsigned short* __restrict__ whh_hi, const unsigned short* __restrict__ whh_lo,
             const float* __restrict__ bih_f, const float* __restrict__ bhh_f,
             const float* __restrict__ bih_b, const float* __restrict__ bhh_b,
             float* __restrict__ out, u64* hbuf) {
  const int bx = blockIdx.x;
  const int g  = bx & 7;                 // group; %8 biases same-XCD placement
  const int nb = bx >> 3;                // 0..31 -> col slice
  const int d  = g & 1;
  const int b0 = (g >> 1) * GM;
  const int tid = threadIdx.x;
  const int lane = tid & 63;
  const int wave = tid >> 6;             // 0..7
  const int lr = lane & 15, lq = lane >> 4;
  const int m = wave >> 2;               // 0: ih (gi, waves 0-3), 1: hh (gh, waves 4-7)
  const int q = wave & 3;                // K-quarter

  __shared__ float part[2][4][3][16][17];    // [matrix][quarter][gate][col][batch]

  // preload weight fragments (loop-invariant): 24 frags = 96 regs
  const size_t wd = (size_t)d * 1536 * HDIM;
  const unsigned short* Whi = (m ? whh_hi : wih_hi) + wd;
  const unsigned short* Wlo = (m ? whh_lo : wih_lo) + wd;
  bf16x8 wh[3][4], wl[3][4];
#pragma unroll
  for (int g3 = 0; g3 < 3; g3++)
#pragma unroll
    for (int kc = 0; kc < 4; kc++) {
      size_t ofs = (size_t)(g3 * HDIM + nb * GC + lr) * HDIM + q * 128 + kc * 32 + lq * 8;
      wh[g3][kc] = *(const bf16x8*)(Whi + ofs);
      wl[g3][kc] = *(const bf16x8*)(Wlo + ofs);
    }

  u64* hb = hbuf + (size_t)g * 2 * NSLOT;   // [2 slots][8192] tagged u64, wire layout

  // gate-thread geometry (waves 0-3; wire stores coalesce)
  const int gb  = tid & 15;
  const int gjj = (tid >> 4) & 1;
  const int gii = (tid >> 5) & 7;
  const int gj  = gjj * 8 + gii;
  const int gw  = (nb >> 3) * 2048 + (((nb >> 1) & 3) * 8 + gii) * 64 +
                  ((nb & 1) * 2 + gjj) * 16 + gb;
  float hreg = 0.f;                      // per-thread fp32 h (exact)
  float bi0 = 0.f, bi1 = 0.f, bi2 = 0.f, bh0 = 0.f, bh1 = 0.f, bh2 = 0.f;
  if (tid < 256) {
    const int col = nb * GC + gj;
    bi0 = (d ? bih_b : bih_f)[col];
    bi1 = (d ? bih_b : bih_f)[HDIM + col];
    bi2 = (d ? bih_b : bih_f)[2 * HDIM + col];
    bh0 = (d ? bhh_b : bhh_f)[col];
    bh1 = (d ? bhh_b : bhh_f)[HDIM + col];
    bh2 = (d ? bhh_b : bhh_f)[2 * HDIM + col];
  }

  u64 cur[4][8];                         // gh in-flight fragment batch
  auto issue_batch = [&](int ss) {
    const u64* rp = hb + (size_t)(ss & 1) * NSLOT + q * 2048 + lane;
#pragma unroll
    for (int kc = 0; kc < 4; kc++)
#pragma unroll
      for (int i = 0; i < 8; i++)
        cur[kc][i] = __hip_atomic_load(rp + (kc * 8 + i) * 64,
                                       __ATOMIC_RELAXED, __HIP_MEMORY_SCOPE_AGENT);
  };
  if (m == 1) issue_batch(0);            // slot0 memset: tag 0 == want 0, h=0

  for (int s = 0; s < T_SEQ; s++) {
    const int t = d ? (T_SEQ - 1 - s) : s;
    f32x4 acc[3];
    acc[0] = f32x4{0.f, 0.f, 0.f, 0.f};
    acc[1] = f32x4{0.f, 0.f, 0.f, 0.f};
    acc[2] = f32x4{0.f, 0.f, 0.f, 0.f};
    float xv = 0.f;
    if (tid < 256)                        // out-path x, issued early (cache-hot)
      xv = x[((size_t)(b0 + gb) * T_SEQ + t) * HDIM + nb * GC + gj];

    if (m == 0) {
      // ---- gi: x fragments from global (overlaps gh poll)
      const float* xrow = x + ((size_t)(b0 + lr) * T_SEQ + t) * HDIM + q * 128 + lq * 8;
      float4 xa[4], xb[4];
#pragma unroll
      for (int kc = 0; kc < 4; kc++) {
        xa[kc] = *(const float4*)(xrow + kc * 32);
        xb[kc] = *(const float4*)(xrow + kc * 32 + 4);
      }
#pragma unroll
      for (int kc = 0; kc < 4; kc++) {
        float xe[8] = {xa[kc].x, xa[kc].y, xa[kc].z, xa[kc].w,
                       xb[kc].x, xb[kc].y, xb[kc].z, xb[kc].w};
        union { u16x8 u; bf16x8 b; } Ah, Al;
#pragma unroll
        for (int i = 0; i < 8; i++) {
          unsigned short hh = f2bf(xe[i]);
          Ah.u[i] = hh;
          Al.u[i] = f2bf(xe[i] - bf2f(hh));
        }
#pragma unroll
        for (int g3 = 0; g3 < 3; g3++) {
          acc[g3] = __builtin_amdgcn_mfma_f32_16x16x32_bf16(Ah.b, wh[g3][kc], acc[g3], 0, 0, 0);
          acc[g3] = __builtin_amdgcn_mfma_f32_16x16x32_bf16(Al.b, wh[g3][kc], acc[g3], 0, 0, 0);
          acc[g3] = __builtin_amdgcn_mfma_f32_16x16x32_bf16(Ah.b, wl[g3][kc], acc[g3], 0, 0, 0);
        }
      }
    } else {
      // ---- gh: poll the pre-issued batch; on failure re-issue ALL 32 words
      // (one latency per round for every chunk — no serialized stale retries)
      const unsigned want = (unsigned)s;
      int it = 0;
      while (true) {
        bool ok = true;
#pragma unroll
        for (int kc = 0; kc < 4; kc++)
#pragma unroll
          for (int i = 0; i < 8; i++)
            ok &= ((unsigned)(cur[kc][i] >> 32) == want);
        if (__all(ok) || ++it > 4096) break;   // cap: wrong-but-terminating
        issue_batch(s);
      }
#pragma unroll
      for (int kc = 0; kc < 4; kc++) {
        union { u16x8 u; bf16x8 b; } Ah, Al;
#pragma unroll
        for (int i = 0; i < 8; i++) {
          unsigned dd = (unsigned)cur[kc][i];
          Ah.u[i] = (unsigned short)(dd >> 16);
          Al.u[i] = (unsigned short)(dd & 0xffffu);
        }
#pragma unroll
        for (int g3 = 0; g3 < 3; g3++) {
          acc[g3] = __builtin_amdgcn_mfma_f32_16x16x32_bf16(Ah.b, wh[g3][kc], acc[g3], 0, 0, 0);
          acc[g3] = __builtin_amdgcn_mfma_f32_16x16x32_bf16(Al.b, wh[g3][kc], acc[g3], 0, 0, 0);
          acc[g3] = __builtin_amdgcn_mfma_f32_16x16x32_bf16(Ah.b, wl[g3][kc], acc[g3], 0, 0, 0);
        }
      }
    }

    // C layout: reg r at (lr,lq) holds D[row=lq*4+r=batch][col=lr]
#pragma unroll
    for (int g3 = 0; g3 < 3; g3++)
#pragma unroll
      for (int r = 0; r < 4; r++)
        part[m][q][g3][lr][lq * 4 + r] = acc[g3][r];
    lds_barrier();

    if (tid < 256) {
      // ---- gates (waves 0-3): fast-math activations, registers for h/bias
      float ir = 0.f, iz = 0.f, inn = 0.f, hr = 0.f, hz = 0.f, hnn = 0.f;
#pragma unroll
      for (int qq = 0; qq < 4; qq++) {
        ir  += part[0][qq][0][gj][gb];
        iz  += part[0][qq][1][gj][gb];
        inn += part[0][qq][2][gj][gb];
        hr  += part[1][qq][0][gj][gb];
        hz  += part[1][qq][1][gj][gb];
        hnn += part[1][qq][2][gj][gb];
      }
      float e1 = __expf(-(ir + bi0 + hr + bh0));
      float rr = __fdividef(1.f, 1.f + e1);
      float e2 = __expf(-(iz + bi1 + hz + bh1));
      float zz = 1.f + e2;                      // note: zz here = 1/sigmoid
      float a  = inn + bi2 + rr * (hnn + bh2);
      float e3 = __expf(-2.f * fabsf(a));
      float nn = copysignf((1.f - e3) * __fdividef(1.f, 1.f + e3), a);
      float sz = __fdividef(1.f, zz);
      float hv = (1.f - sz) * nn + sz * hreg;
      hv = nn + sz * (hreg - nn);               // fused form (same value)
      hreg = hv;
      unsigned short h16 = f2bf(hv);
      unsigned short l16 = f2bf(hv - bf2f(h16));
      // tagged store: data + readiness in one 8B word, fire-and-forget
      u64* wr = hb + (size_t)((s + 1) & 1) * NSLOT;
      u64 wv = ((u64)(unsigned)(s + 1) << 32) |
               (u64)(((unsigned)h16 << 16) | (unsigned)l16);
      __hip_atomic_store(wr + gw, wv, __ATOMIC_RELAXED, __HIP_MEMORY_SCOPE_AGENT);
      if (s >= CTXN && s < T_SEQ - CTXN)
        out[((size_t)(b0 + gb) * OUT_T + (s - CTXN)) * 1024 + d * HDIM + nb * GC + gj] = hv + xv;
    } else if (s + 1 < T_SEQ) {
      issue_batch(s + 1);                // gh: speculative pre-issue (tag-checked)
    }
    lds_barrier();                       // protect part[] for next step
  }
}

extern "C" void kernel_launch(void* const* d_in, const int* in_sizes, int n_in,
                              void* d_out, int out_size, void* d_ws, size_t ws_size,
                              hipStream_t stream) {
  (void)in_sizes; (void)n_in; (void)out_size; (void)ws_size;
  const float* v_in  = (const float*)d_in[0];
  const float* Wih_f = (const float*)d_in[1];
  const float* Whh_f = (const float*)d_in[2];
  const float* bih_f = (const float*)d_in[3];
  const float* bhh_f = (const float*)d_in[4];
  const float* Wih_b = (const float*)d_in[5];
  const float* Whh_b = (const float*)d_in[6];
  const float* bih_b = (const float*)d_in[7];
  const float* bhh_b = (const float*)d_in[8];
  float* out = (float*)d_out;
  char* ws = (char*)d_ws;

  // ws layout (~13 MB total):
  //   [0, 1M)         hbuf : 8 groups x 2 slots x 8192 tagged u64 (wire layout)
  //   [1M,  +3M)      wih_hi [2][1536][512] bf16
  //   [4M,  +3M)      wih_lo
  //   [7M,  +3M)      whh_hi
  //   [10M, +3M)      whh_lo
  u64* hbuf = (u64*)ws;
  unsigned short* wih_hi = (unsigned short*)(ws + (size_t)(1 << 20));
  unsigned short* wih_lo = (unsigned short*)(ws + (size_t)(4 << 20));
  unsigned short* whh_hi = (unsigned short*)(ws + (size_t)(7 << 20));
  unsigned short* whh_lo = (unsigned short*)(ws + (size_t)(10 << 20));

  // zero hbuf: slot0 tag=0 data=0 == valid h(0)=0; slot1 tag 0 != 1 -> polled
  hipMemsetAsync(ws, 0, (size_t)8 * 2 * NSLOT * 8, stream);
  split_w<<<dim3(768, 4), 256, 0, stream>>>(Wih_f, Wih_b, Whh_f, Whh_b,
                                            wih_hi, wih_lo, whh_hi, whh_lo);
  gru_rec<<<256, 512, 0, stream>>>(v_in, wih_hi, wih_lo, whh_hi, whh_lo,
                                   bih_f, bhh_f, bih_b, bhh_b, out, hbuf);
}

// Round 4
// 2187.054 us; speedup vs baseline: 1.2134x; 1.2134x over previous
//
#include <hip/hip_runtime.h>
#include <stdint.h>
#include <stddef.h>

#define T_SEQ 512
#define HDIM 512
#define CTXN 10
#define OUT_T (T_SEQ - 2 * CTXN)   // 492
#define GM 16
#define GC 16
#define NSLOT 8192                 // GM*HDIM u64 words per ring slot

typedef __bf16 bf16x8 __attribute__((ext_vector_type(8)));
typedef float f32x4 __attribute__((ext_vector_type(4)));
typedef unsigned short u16x4 __attribute__((ext_vector_type(4)));
typedef unsigned short u16x8 __attribute__((ext_vector_type(8)));
typedef unsigned long long u64;

__device__ __forceinline__ unsigned short f2bf(float f) {
  union { float f; unsigned u; } v; v.f = f;
  unsigned r = v.u + 0x7FFFu + ((v.u >> 16) & 1u);  // RNE
  return (unsigned short)(r >> 16);
}
__device__ __forceinline__ float bf2f(unsigned short b) {
  union { unsigned u; float f; } v; v.u = ((unsigned)b) << 16;
  return v.f;
}

// LDS-only barrier: orders ds ops across the workgroup WITHOUT draining vmcnt
// (keeps prefetched x loads and fire-and-forget h/out stores in flight).
__device__ __forceinline__ void lds_barrier() {
  asm volatile("s_waitcnt lgkmcnt(0)" ::: "memory");
  __builtin_amdgcn_s_barrier();
  __builtin_amdgcn_sched_barrier(0);
}

// ------------- split fp32 weights into (hi, lo) bf16 pairs -------------
__global__ void split_w(const float* __restrict__ wih_f, const float* __restrict__ wih_b,
                        const float* __restrict__ whh_f, const float* __restrict__ whh_b,
                        unsigned short* __restrict__ wih_hi, unsigned short* __restrict__ wih_lo,
                        unsigned short* __restrict__ whh_hi, unsigned short* __restrict__ whh_lo) {
  const int which = blockIdx.y;
  const float* src = which == 0 ? wih_f : which == 1 ? wih_b : which == 2 ? whh_f : whh_b;
  const size_t off = (which & 1) ? (size_t)1536 * HDIM : 0;
  unsigned short* dhi = (which < 2 ? wih_hi : whh_hi) + off;
  unsigned short* dlo = (which < 2 ? wih_lo : whh_lo) + off;
  size_t i = ((size_t)blockIdx.x * 256 + threadIdx.x) * 4;
  float4 v = *(const float4*)(src + i);
  u16x4 h, l;
  h.x = f2bf(v.x); l.x = f2bf(v.x - bf2f(h.x));
  h.y = f2bf(v.y); l.y = f2bf(v.y - bf2f(h.y));
  h.z = f2bf(v.z); l.z = f2bf(v.z - bf2f(h.z));
  h.w = f2bf(v.w); l.w = f2bf(v.w - bf2f(h.w));
  *(u16x4*)(dhi + i) = h;
  *(u16x4*)(dlo + i) = l;
}

// ------------- fused split-precision bidirectional GRU recurrence -------------
// 8 groups = (4 batch chunks of 16) x (2 dirs); 32 blocks/group (one XCD each
// via bx&7 round-robin).  h exchange: tagged u64 {tag=step | (hi16|lo16)} in a
// depth-2 ring, wire layout = MFMA fragment order (coalesced both sides).
// Poll = round-2 verbatim (issue 32 at step top AFTER the barrier — stores from
// all blocks have ~landed by then — then per-kc check, 8-word reload + s_sleep
// backoff; NO speculative pre-issue: round 3 proved it is guaranteed-stale and
// quantizes detect to full-batch round trips).
// New vs round 2: x register double-buffer prefetch (removes the per-step HBM
// miss from the gi critical chain), LDS-only barriers, __expf gates, h/bias in
// registers, gi+gates on waves 0-3 / gh on 4-7 (gh polls immediately after the
// barrier, never delayed by gate work).
// Depth-2 safety: a block stores tag s+1 only after observing all tags==s,
// which implies every block retired its slot((s+1)&1) reads.
__global__ __launch_bounds__(512)
void gru_rec(const float* __restrict__ x,
             const unsigned short* __restrict__ wih_hi, const unsigned short* __restrict__ wih_lo,
             const unsigned short* __restrict__ whh_hi, const unsigned short* __restrict__ whh_lo,
             const float* __restrict__ bih_f, const float* __restrict__ bhh_f,
             const float* __restrict__ bih_b, const float* __restrict__ bhh_b,
             float* __restrict__ out, u64* hbuf) {
  const int bx = blockIdx.x;
  const int g  = bx & 7;                 // group == XCD (round-robin placement)
  const int nb = bx >> 3;                // 0..31 -> col slice
  const int d  = g & 1;
  const int b0 = (g >> 1) * GM;
  const int tid = threadIdx.x;
  const int lane = tid & 63;
  const int wave = tid >> 6;             // 0..7
  const int lr = lane & 15, lq = lane >> 4;
  const int m = wave >> 2;               // 0: ih (gi, waves 0-3), 1: hh (gh, waves 4-7)
  const int q = wave & 3;                // K-quarter

  __shared__ float part[2][4][3][16][17];    // [matrix][quarter][gate][col][batch]

  // preload weight fragments (loop-invariant): 24 frags = 96 regs
  const size_t wd = (size_t)d * 1536 * HDIM;
  const unsigned short* Whi = (m ? whh_hi : wih_hi) + wd;
  const unsigned short* Wlo = (m ? whh_lo : wih_lo) + wd;
  bf16x8 wh[3][4], wl[3][4];
#pragma unroll
  for (int g3 = 0; g3 < 3; g3++)
#pragma unroll
    for (int kc = 0; kc < 4; kc++) {
      size_t ofs = (size_t)(g3 * HDIM + nb * GC + lr) * HDIM + q * 128 + kc * 32 + lq * 8;
      wh[g3][kc] = *(const bf16x8*)(Whi + ofs);
      wl[g3][kc] = *(const bf16x8*)(Wlo + ofs);
    }

  u64* hb = hbuf + (size_t)g * 2 * NSLOT;   // [2 slots][8192] tagged u64, wire layout

  // gate-thread geometry (waves 0-3; wire stores coalesce)
  const int gb  = tid & 15;
  const int gjj = (tid >> 4) & 1;
  const int gii = (tid >> 5) & 7;
  const int gj  = gjj * 8 + gii;
  const int gw  = (nb >> 3) * 2048 + (((nb >> 1) & 3) * 8 + gii) * 64 +
                  ((nb & 1) * 2 + gjj) * 16 + gb;
  float hreg = 0.f;                      // per-thread fp32 h (exact)
  float bi0 = 0.f, bi1 = 0.f, bi2 = 0.f, bh0 = 0.f, bh1 = 0.f, bh2 = 0.f;
  if (tid < 256) {
    const int col = nb * GC + gj;
    bi0 = (d ? bih_b : bih_f)[col];
    bi1 = (d ? bih_b : bih_f)[HDIM + col];
    bi2 = (d ? bih_b : bih_f)[2 * HDIM + col];
    bh0 = (d ? bhh_b : bhh_f)[col];
    bh1 = (d ? bhh_b : bhh_f)[HDIM + col];
    bh2 = (d ? bhh_b : bhh_f)[2 * HDIM + col];
  }

  // gi x fragments: register double-buffer (prefetch one step ahead)
  float4 xc0[4], xc1[4];                 // current step's fragments
  if (m == 0) {
    const int t0 = d ? (T_SEQ - 1) : 0;
    const float* xr = x + ((size_t)(b0 + lr) * T_SEQ + t0) * HDIM + q * 128 + lq * 8;
#pragma unroll
    for (int kc = 0; kc < 4; kc++) {
      xc0[kc] = *(const float4*)(xr + kc * 32);
      xc1[kc] = *(const float4*)(xr + kc * 32 + 4);
    }
  }

  for (int s = 0; s < T_SEQ; s++) {
    const int t = d ? (T_SEQ - 1 - s) : s;
    f32x4 acc[3];
    acc[0] = f32x4{0.f, 0.f, 0.f, 0.f};
    acc[1] = f32x4{0.f, 0.f, 0.f, 0.f};
    acc[2] = f32x4{0.f, 0.f, 0.f, 0.f};
    float xv = 0.f;
    if (tid < 256)                        // line is L2/L1-hot from last prefetch
      xv = x[((size_t)(b0 + gb) * T_SEQ + t) * HDIM + nb * GC + gj];

    if (m == 0) {
      // ---- issue prefetch for s+1 first (overlaps everything below)
      float4 xn0[4], xn1[4];
      const int sn = (s + 1 < T_SEQ) ? s + 1 : s;
      const int tn = d ? (T_SEQ - 1 - sn) : sn;
      const float* xrn = x + ((size_t)(b0 + lr) * T_SEQ + tn) * HDIM + q * 128 + lq * 8;
#pragma unroll
      for (int kc = 0; kc < 4; kc++) {
        xn0[kc] = *(const float4*)(xrn + kc * 32);
        xn1[kc] = *(const float4*)(xrn + kc * 32 + 4);
      }
      // ---- gi MFMA from current registers
#pragma unroll
      for (int kc = 0; kc < 4; kc++) {
        float xe[8] = {xc0[kc].x, xc0[kc].y, xc0[kc].z, xc0[kc].w,
                       xc1[kc].x, xc1[kc].y, xc1[kc].z, xc1[kc].w};
        union { u16x8 u; bf16x8 b; } Ah, Al;
#pragma unroll
        for (int i = 0; i < 8; i++) {
          unsigned short hh = f2bf(xe[i]);
          Ah.u[i] = hh;
          Al.u[i] = f2bf(xe[i] - bf2f(hh));
        }
#pragma unroll
        for (int g3 = 0; g3 < 3; g3++) {
          acc[g3] = __builtin_amdgcn_mfma_f32_16x16x32_bf16(Ah.b, wh[g3][kc], acc[g3], 0, 0, 0);
          acc[g3] = __builtin_amdgcn_mfma_f32_16x16x32_bf16(Al.b, wh[g3][kc], acc[g3], 0, 0, 0);
          acc[g3] = __builtin_amdgcn_mfma_f32_16x16x32_bf16(Ah.b, wl[g3][kc], acc[g3], 0, 0, 0);
        }
      }
#pragma unroll
      for (int kc = 0; kc < 4; kc++) { xc0[kc] = xn0[kc]; xc1[kc] = xn1[kc]; }
    } else {
      // ---- gh: round-2 poll verbatim (issue all 32, per-kc check, 8-word
      // reload + s_sleep backoff)
      const u64* rp = hb + (size_t)(s & 1) * NSLOT + q * 2048 + lane;
      const unsigned want = (unsigned)s;
      u64 cur[4][8];
#pragma unroll
      for (int kc = 0; kc < 4; kc++)
#pragma unroll
        for (int i = 0; i < 8; i++)
          cur[kc][i] = __hip_atomic_load(rp + (kc * 8 + i) * 64,
                                         __ATOMIC_RELAXED, __HIP_MEMORY_SCOPE_AGENT);
#pragma unroll
      for (int kc = 0; kc < 4; kc++) {
        int it = 0;
        while (true) {
          bool ok = true;
#pragma unroll
          for (int i = 0; i < 8; i++) ok &= ((unsigned)(cur[kc][i] >> 32) == want);
          if (ok || ++it > (1 << 18)) break;   // cap: wrong-but-terminating
          __builtin_amdgcn_s_sleep(1);         // bound poll traffic
#pragma unroll
          for (int i = 0; i < 8; i++)
            cur[kc][i] = __hip_atomic_load(rp + (kc * 8 + i) * 64,
                                           __ATOMIC_RELAXED, __HIP_MEMORY_SCOPE_AGENT);
        }
        union { u16x8 u; bf16x8 b; } Ah, Al;
#pragma unroll
        for (int i = 0; i < 8; i++) {
          unsigned dd = (unsigned)cur[kc][i];
          Ah.u[i] = (unsigned short)(dd >> 16);
          Al.u[i] = (unsigned short)(dd & 0xffffu);
        }
#pragma unroll
        for (int g3 = 0; g3 < 3; g3++) {
          acc[g3] = __builtin_amdgcn_mfma_f32_16x16x32_bf16(Ah.b, wh[g3][kc], acc[g3], 0, 0, 0);
          acc[g3] = __builtin_amdgcn_mfma_f32_16x16x32_bf16(Al.b, wh[g3][kc], acc[g3], 0, 0, 0);
          acc[g3] = __builtin_amdgcn_mfma_f32_16x16x32_bf16(Ah.b, wl[g3][kc], acc[g3], 0, 0, 0);
        }
      }
    }

    // C layout: reg r at (lr,lq) holds D[row=lq*4+r=batch][col=lr]
#pragma unroll
    for (int g3 = 0; g3 < 3; g3++)
#pragma unroll
      for (int r = 0; r < 4; r++)
        part[m][q][g3][lr][lq * 4 + r] = acc[g3][r];
    lds_barrier();

    if (tid < 256) {
      // ---- gates (waves 0-3): fast-math activations, h/bias in registers
      float ir = 0.f, iz = 0.f, inn = 0.f, hr = 0.f, hz = 0.f, hnn = 0.f;
#pragma unroll
      for (int qq = 0; qq < 4; qq++) {
        ir  += part[0][qq][0][gj][gb];
        iz  += part[0][qq][1][gj][gb];
        inn += part[0][qq][2][gj][gb];
        hr  += part[1][qq][0][gj][gb];
        hz  += part[1][qq][1][gj][gb];
        hnn += part[1][qq][2][gj][gb];
      }
      float e1 = __expf(-(ir + bi0 + hr + bh0));
      float rr = __fdividef(1.f, 1.f + e1);
      float e2 = __expf(-(iz + bi1 + hz + bh1));
      float sz = __fdividef(1.f, 1.f + e2);
      float a  = inn + bi2 + rr * (hnn + bh2);
      float e3 = __expf(-2.f * fabsf(a));
      float nn = copysignf((1.f - e3) * __fdividef(1.f, 1.f + e3), a);
      float hv = nn + sz * (hreg - nn);
      hreg = hv;
      unsigned short h16 = f2bf(hv);
      unsigned short l16 = f2bf(hv - bf2f(h16));
      // tagged store: data + readiness in one 8B word, fire-and-forget
      u64* wr = hb + (size_t)((s + 1) & 1) * NSLOT;
      u64 wv = ((u64)(unsigned)(s + 1) << 32) |
               (u64)(((unsigned)h16 << 16) | (unsigned)l16);
      __hip_atomic_store(wr + gw, wv, __ATOMIC_RELAXED, __HIP_MEMORY_SCOPE_AGENT);
      if (s >= CTXN && s < T_SEQ - CTXN)
        out[((size_t)(b0 + gb) * OUT_T + (s - CTXN)) * 1024 + d * HDIM + nb * GC + gj] = hv + xv;
    }
    lds_barrier();                       // gh polls for s+1 only after stores issued
  }
}

extern "C" void kernel_launch(void* const* d_in, const int* in_sizes, int n_in,
                              void* d_out, int out_size, void* d_ws, size_t ws_size,
                              hipStream_t stream) {
  (void)in_sizes; (void)n_in; (void)out_size; (void)ws_size;
  const float* v_in  = (const float*)d_in[0];
  const float* Wih_f = (const float*)d_in[1];
  const float* Whh_f = (const float*)d_in[2];
  const float* bih_f = (const float*)d_in[3];
  const float* bhh_f = (const float*)d_in[4];
  const float* Wih_b = (const float*)d_in[5];
  const float* Whh_b = (const float*)d_in[6];
  const float* bih_b = (const float*)d_in[7];
  const float* bhh_b = (const float*)d_in[8];
  float* out = (float*)d_out;
  char* ws = (char*)d_ws;

  // ws layout (~13 MB total):
  //   [0, 1M)         hbuf : 8 groups x 2 slots x 8192 tagged u64 (wire layout)
  //   [1M,  +3M)      wih_hi [2][1536][512] bf16
  //   [4M,  +3M)      wih_lo
  //   [7M,  +3M)      whh_hi
  //   [10M, +3M)      whh_lo
  u64* hbuf = (u64*)ws;
  unsigned short* wih_hi = (unsigned short*)(ws + (size_t)(1 << 20));
  unsigned short* wih_lo = (unsigned short*)(ws + (size_t)(4 << 20));
  unsigned short* whh_hi = (unsigned short*)(ws + (size_t)(7 << 20));
  unsigned short* whh_lo = (unsigned short*)(ws + (size_t)(10 << 20));

  // zero hbuf: slot0 tag=0 data=0 == valid h(0)=0; slot1 tag 0 != 1 -> polled
  hipMemsetAsync(ws, 0, (size_t)8 * 2 * NSLOT * 8, stream);
  split_w<<<dim3(768, 4), 256, 0, stream>>>(Wih_f, Wih_b, Whh_f, Whh_b,
                                            wih_hi, wih_lo, whh_hi, whh_lo);
  gru_rec<<<256, 512, 0, stream>>>(v_in, wih_hi, wih_lo, whh_hi, whh_lo,
                                   bih_f, bhh_f, bih_b, bhh_b, out, hbuf);
}

// Round 5
// 2065.117 us; speedup vs baseline: 1.2850x; 1.0590x over previous
//
#include <hip/hip_runtime.h>
#include <stdint.h>
#include <stddef.h>

#define T_SEQ 512
#define HDIM 512
#define CTXN 10
#define OUT_T (T_SEQ - 2 * CTXN)   // 492
#define GM 16
#define GC 16
#define NSLOT 8192                 // GM*HDIM u32 words per ring slot (4B wire)

typedef __bf16 bf16x8 __attribute__((ext_vector_type(8)));
typedef float f32x4 __attribute__((ext_vector_type(4)));
typedef unsigned short u16x4 __attribute__((ext_vector_type(4)));
typedef unsigned short u16x8 __attribute__((ext_vector_type(8)));
typedef unsigned long long u64;

__device__ __forceinline__ unsigned short f2bf(float f) {
  union { float f; unsigned u; } v; v.f = f;
  unsigned r = v.u + 0x7FFFu + ((v.u >> 16) & 1u);  // RNE
  return (unsigned short)(r >> 16);
}
__device__ __forceinline__ float bf2f(unsigned short b) {
  union { unsigned u; float f; } v; v.u = ((unsigned)b) << 16;
  return v.f;
}
__device__ __forceinline__ unsigned f2u(float f) {
  union { float f; unsigned u; } v; v.f = f; return v.u;
}
__device__ __forceinline__ float u2f(unsigned u) {
  union { unsigned u; float f; } v; v.u = u; return v.f;
}

// ------------- split fp32 weights into (hi, lo) bf16 pairs -------------
// Also (re)initializes the h ring buffer every launch:
//   slot0 = 0x00000000  (h=0, tagbit=0  -> valid h(0))
//   slot1 = 0x40000000  (tagbit=1 != want(s=1)=0 -> polled until written)
__global__ void split_w(const float* __restrict__ wih_f, const float* __restrict__ wih_b,
                        const float* __restrict__ whh_f, const float* __restrict__ whh_b,
                        unsigned short* __restrict__ wih_hi, unsigned short* __restrict__ wih_lo,
                        unsigned short* __restrict__ whh_hi, unsigned short* __restrict__ whh_lo,
                        unsigned* __restrict__ hbuf) {
  const int which = blockIdx.y;
  if (which == 0) {
    size_t k = (size_t)blockIdx.x * 256 + threadIdx.x;   // 0..196607
    if (k < (size_t)8 * 2 * NSLOT)                       // 131072 words
      hbuf[k] = ((k >> 13) & 1) ? 0x40000000u : 0u;      // [g][slot][8192]
  }
  const float* src = which == 0 ? wih_f : which == 1 ? wih_b : which == 2 ? whh_f : whh_b;
  const size_t off = (which & 1) ? (size_t)1536 * HDIM : 0;
  unsigned short* dhi = (which < 2 ? wih_hi : whh_hi) + off;
  unsigned short* dlo = (which < 2 ? wih_lo : whh_lo) + off;
  size_t i = ((size_t)blockIdx.x * 256 + threadIdx.x) * 4;
  float4 v = *(const float4*)(src + i);
  u16x4 h, l;
  h.x = f2bf(v.x); l.x = f2bf(v.x - bf2f(h.x));
  h.y = f2bf(v.y); l.y = f2bf(v.y - bf2f(h.y));
  h.z = f2bf(v.z); l.z = f2bf(v.z - bf2f(h.z));
  h.w = f2bf(v.w); l.w = f2bf(v.w - bf2f(h.w));
  *(u16x4*)(dhi + i) = h;
  *(u16x4*)(dlo + i) = l;
}

// ------------- fused split-precision bidirectional GRU recurrence -------------
// 8 groups = (4 batch chunks of 16) x (2 dirs); 32 blocks/group (same-XCD via
// bx&7 round-robin — perf heuristic only).
// h exchange (NEW): 4-byte wire word = exact fp32 h with BIT30 REPURPOSED as a
// 1-bit step tag.  |h| < 1 guarantees the fp32 exponent MSB (bit30) is 0, so
// the bit is free; depth-2 ring only ever exposes tags {s-2, s} in a polled
// slot and tagbit = (s>>1)&1 flips on every slot revisit, so 1 bit fully
// disambiguates.  Halves h wire traffic (store AND poll) vs the tagged-u64
// wire, and the wire is now lossless fp32.  Wire layout = MFMA fragment order
// (coalesced both sides); the store IS the flag (single-copy atomic 4B).
// Readers split h -> bf16 hi/lo in-register (trunc split, err ~2^-16).
// Poll = round-2 verbatim: issue all 32 words, per-kc tag check, 8-word
// reload + s_sleep backoff.  Barriers = __syncthreads (r2-verified).
// Depth-2 safety: a block stores tag(s+1) only after observing all tags==s,
// which implies every block retired its slot((s+1)&1) reads (transitive
// through the previous step's store-after-consume ordering).
__global__ __launch_bounds__(512)
void gru_rec(const float* __restrict__ x,
             const unsigned short* __restrict__ wih_hi, const unsigned short* __restrict__ wih_lo,
             const unsigned short* __restrict__ whh_hi, const unsigned short* __restrict__ whh_lo,
             const float* __restrict__ bih_f, const float* __restrict__ bhh_f,
             const float* __restrict__ bih_b, const float* __restrict__ bhh_b,
             float* __restrict__ out, unsigned* hbuf) {
  const int bx = blockIdx.x;
  const int g  = bx & 7;                 // group; %8 biases same-XCD placement
  const int nb = bx >> 3;                // 0..31 -> col slice
  const int d  = g & 1;
  const int b0 = (g >> 1) * GM;
  const int tid = threadIdx.x;
  const int lane = tid & 63;
  const int wave = tid >> 6;             // 0..7
  const int lr = lane & 15, lq = lane >> 4;
  const int m = wave >> 2;               // 0: ih (gi, waves 0-3), 1: hh (gh, waves 4-7)
  const int q = wave & 3;                // K-quarter

  __shared__ float part[2][4][3][16][17];    // [matrix][quarter][gate][col][batch]

  // preload weight fragments (loop-invariant): 24 frags = 96 regs
  const size_t wd = (size_t)d * 1536 * HDIM;
  const unsigned short* Whi = (m ? whh_hi : wih_hi) + wd;
  const unsigned short* Wlo = (m ? whh_lo : wih_lo) + wd;
  bf16x8 wh[3][4], wl[3][4];
#pragma unroll
  for (int g3 = 0; g3 < 3; g3++)
#pragma unroll
    for (int kc = 0; kc < 4; kc++) {
      size_t ofs = (size_t)(g3 * HDIM + nb * GC + lr) * HDIM + q * 128 + kc * 32 + lq * 8;
      wh[g3][kc] = *(const bf16x8*)(Whi + ofs);
      wl[g3][kc] = *(const bf16x8*)(Wlo + ofs);
    }

  unsigned* hb = hbuf + (size_t)g * 2 * NSLOT;   // [2 slots][8192] u32, wire layout

  // gate-thread geometry (waves 0-3; wire stores coalesce)
  const int gb  = tid & 15;
  const int gjj = (tid >> 4) & 1;
  const int gii = (tid >> 5) & 7;
  const int gj  = gjj * 8 + gii;
  const int gw  = (nb >> 3) * 2048 + (((nb >> 1) & 3) * 8 + gii) * 64 +
                  ((nb & 1) * 2 + gjj) * 16 + gb;
  float hreg = 0.f;                      // per-thread fp32 h (exact)
  float bi0 = 0.f, bi1 = 0.f, bi2 = 0.f, bh0 = 0.f, bh1 = 0.f, bh2 = 0.f;
  if (tid < 256) {
    const int col = nb * GC + gj;
    bi0 = (d ? bih_b : bih_f)[col];
    bi1 = (d ? bih_b : bih_f)[HDIM + col];
    bi2 = (d ? bih_b : bih_f)[2 * HDIM + col];
    bh0 = (d ? bhh_b : bhh_f)[col];
    bh1 = (d ? bhh_b : bhh_f)[HDIM + col];
    bh2 = (d ? bhh_b : bhh_f)[2 * HDIM + col];
  }

  for (int s = 0; s < T_SEQ; s++) {
    const int t = d ? (T_SEQ - 1 - s) : s;
    f32x4 acc[3];
    acc[0] = f32x4{0.f, 0.f, 0.f, 0.f};
    acc[1] = f32x4{0.f, 0.f, 0.f, 0.f};
    acc[2] = f32x4{0.f, 0.f, 0.f, 0.f};
    float xv = 0.f;
    if (tid < 256)                        // out-path x (cache-hot from gi reads)
      xv = x[((size_t)(b0 + gb) * T_SEQ + t) * HDIM + nb * GC + gj];

    if (m == 0) {
      // ---- gi: x fragments from global (overlaps gh poll)
      const float* xrow = x + ((size_t)(b0 + lr) * T_SEQ + t) * HDIM + q * 128 + lq * 8;
      float4 xa[4], xb[4];
#pragma unroll
      for (int kc = 0; kc < 4; kc++) {
        xa[kc] = *(const float4*)(xrow + kc * 32);
        xb[kc] = *(const float4*)(xrow + kc * 32 + 4);
      }
#pragma unroll
      for (int kc = 0; kc < 4; kc++) {
        float xe[8] = {xa[kc].x, xa[kc].y, xa[kc].z, xa[kc].w,
                       xb[kc].x, xb[kc].y, xb[kc].z, xb[kc].w};
        union { u16x8 u; bf16x8 b; } Ah, Al;
#pragma unroll
        for (int i = 0; i < 8; i++) {
          unsigned short hh = f2bf(xe[i]);
          Ah.u[i] = hh;
          Al.u[i] = f2bf(xe[i] - bf2f(hh));
        }
#pragma unroll
        for (int g3 = 0; g3 < 3; g3++) {
          acc[g3] = __builtin_amdgcn_mfma_f32_16x16x32_bf16(Ah.b, wh[g3][kc], acc[g3], 0, 0, 0);
          acc[g3] = __builtin_amdgcn_mfma_f32_16x16x32_bf16(Al.b, wh[g3][kc], acc[g3], 0, 0, 0);
          acc[g3] = __builtin_amdgcn_mfma_f32_16x16x32_bf16(Ah.b, wl[g3][kc], acc[g3], 0, 0, 0);
        }
      }
    } else {
      // ---- gh: coalesced 4B tagged-fp32 fragment loads -> registers
      const unsigned* rp = hb + (size_t)(s & 1) * NSLOT + q * 2048 + lane;
      const unsigned want = ((unsigned)s >> 1) & 1u;
      unsigned cur[4][8];
#pragma unroll
      for (int kc = 0; kc < 4; kc++)      // fire all 32 coalesced loads (MLP)
#pragma unroll
        for (int i = 0; i < 8; i++)
          cur[kc][i] = __hip_atomic_load(rp + (kc * 8 + i) * 64,
                                         __ATOMIC_RELAXED, __HIP_MEMORY_SCOPE_AGENT);
#pragma unroll
      for (int kc = 0; kc < 4; kc++) {
        int it = 0;
        while (true) {
          bool ok = true;
#pragma unroll
          for (int i = 0; i < 8; i++)
            ok &= (((cur[kc][i] >> 30) ^ want) & 1u) == 0u;
          if (ok || ++it > (1 << 18)) break;   // cap: wrong-but-terminating
          __builtin_amdgcn_s_sleep(1);         // bound poll traffic
#pragma unroll
          for (int i = 0; i < 8; i++)
            cur[kc][i] = __hip_atomic_load(rp + (kc * 8 + i) * 64,
                                           __ATOMIC_RELAXED, __HIP_MEMORY_SCOPE_AGENT);
        }
        union { u16x8 u; bf16x8 b; } Ah, Al;
#pragma unroll
        for (int i = 0; i < 8; i++) {
          unsigned hw  = cur[kc][i] & 0xBFFFFFFFu;   // clear tag bit (bit30=0)
          unsigned hiu = hw & 0xFFFF0000u;
          float    rsd = u2f(hw) - u2f(hiu);         // exact low-16 residual
          Ah.u[i] = (unsigned short)(hiu >> 16);
          Al.u[i] = (unsigned short)(f2u(rsd) >> 16);
        }
#pragma unroll
        for (int g3 = 0; g3 < 3; g3++) {
          acc[g3] = __builtin_amdgcn_mfma_f32_16x16x32_bf16(Ah.b, wh[g3][kc], acc[g3], 0, 0, 0);
          acc[g3] = __builtin_amdgcn_mfma_f32_16x16x32_bf16(Al.b, wh[g3][kc], acc[g3], 0, 0, 0);
          acc[g3] = __builtin_amdgcn_mfma_f32_16x16x32_bf16(Ah.b, wl[g3][kc], acc[g3], 0, 0, 0);
        }
      }
    }

    // C layout: reg r at (lr,lq) holds D[row=lq*4+r=batch][col=lr]
#pragma unroll
    for (int g3 = 0; g3 < 3; g3++)
#pragma unroll
      for (int r = 0; r < 4; r++)
        part[m][q][g3][lr][lq * 4 + r] = acc[g3][r];
    __syncthreads();

    if (tid < 256) {
      // ---- gates (waves 0-3 = gi waves, so gh waves poll s+1 immediately)
      float ir = 0.f, iz = 0.f, inn = 0.f, hr = 0.f, hz = 0.f, hnn = 0.f;
#pragma unroll
      for (int qq = 0; qq < 4; qq++) {
        ir  += part[0][qq][0][gj][gb];
        iz  += part[0][qq][1][gj][gb];
        inn += part[0][qq][2][gj][gb];
        hr  += part[1][qq][0][gj][gb];
        hz  += part[1][qq][1][gj][gb];
        hnn += part[1][qq][2][gj][gb];
      }
      float e1 = __expf(-(ir + bi0 + hr + bh0));
      float rr = __fdividef(1.f, 1.f + e1);
      float e2 = __expf(-(iz + bi1 + hz + bh1));
      float sz = __fdividef(1.f, 1.f + e2);
      float a  = inn + bi2 + rr * (hnn + bh2);
      float e3 = __expf(-2.f * fabsf(a));
      float nn = copysignf((1.f - e3) * __fdividef(1.f, 1.f + e3), a);
      float hv = nn + sz * (hreg - nn);
      hreg = hv;
      // 4B wire word: exact fp32 h, bit30 = tagbit for step s+1
      unsigned tb = (((unsigned)(s + 1)) >> 1) & 1u;
      unsigned wv = (f2u(hv) & 0xBFFFFFFFu) | (tb << 30);
      unsigned* wr = hb + (size_t)((s + 1) & 1) * NSLOT;
      __hip_atomic_store(wr + gw, wv, __ATOMIC_RELAXED, __HIP_MEMORY_SCOPE_AGENT);
      if (s >= CTXN && s < T_SEQ - CTXN)
        out[((size_t)(b0 + gb) * OUT_T + (s - CTXN)) * 1024 + d * HDIM + nb * GC + gj] = hv + xv;
    }
    __syncthreads();                     // protect part[] for next step
  }
}

extern "C" void kernel_launch(void* const* d_in, const int* in_sizes, int n_in,
                              void* d_out, int out_size, void* d_ws, size_t ws_size,
                              hipStream_t stream) {
  (void)in_sizes; (void)n_in; (void)out_size; (void)ws_size;
  const float* v_in  = (const float*)d_in[0];
  const float* Wih_f = (const float*)d_in[1];
  const float* Whh_f = (const float*)d_in[2];
  const float* bih_f = (const float*)d_in[3];
  const float* bhh_f = (const float*)d_in[4];
  const float* Wih_b = (const float*)d_in[5];
  const float* Whh_b = (const float*)d_in[6];
  const float* bih_b = (const float*)d_in[7];
  const float* bhh_b = (const float*)d_in[8];
  float* out = (float*)d_out;
  char* ws = (char*)d_ws;

  // ws layout (~13 MB total):
  //   [0, 512K)       hbuf : 8 groups x 2 slots x 8192 u32 (fp32+tagbit wire)
  //   [1M,  +3M)      wih_hi [2][1536][512] bf16
  //   [4M,  +3M)      wih_lo
  //   [7M,  +3M)      whh_hi
  //   [10M, +3M)      whh_lo
  unsigned* hbuf = (unsigned*)ws;
  unsigned short* wih_hi = (unsigned short*)(ws + (size_t)(1 << 20));
  unsigned short* wih_lo = (unsigned short*)(ws + (size_t)(4 << 20));
  unsigned short* whh_hi = (unsigned short*)(ws + (size_t)(7 << 20));
  unsigned short* whh_lo = (unsigned short*)(ws + (size_t)(10 << 20));

  // hbuf init (incl. slot1 = 0x40000000) is done inside split_w each launch.
  split_w<<<dim3(768, 4), 256, 0, stream>>>(Wih_f, Wih_b, Whh_f, Whh_b,
                                            wih_hi, wih_lo, whh_hi, whh_lo, hbuf);
  gru_rec<<<256, 512, 0, stream>>>(v_in, wih_hi, wih_lo, whh_hi, whh_lo,
                                   bih_f, bhh_f, bih_b, bhh_b, out, hbuf);
}